// Round 4
// baseline (250.388 us; speedup 1.0000x reference)
//
#include <hip/hip_runtime.h>
#include <hip/hip_bf16.h>
#include <math.h>

#define DIM 1024
#define HID 64
#define SD  32
#define NS  64
#define TM  128
#define LRc 0.01f
#define EPSc 1e-8f

typedef __attribute__((ext_vector_type(8))) short bf16x8;
typedef __attribute__((ext_vector_type(4))) float f32x4;

__device__ __forceinline__ unsigned short f2bf(float f) {
    union { __hip_bfloat16 h; unsigned short u; } cv;
    cv.h = __float2bfloat16(f);
    return cv.u;
}
__device__ __forceinline__ float bf2f(unsigned short u) {
    union { unsigned short u; __hip_bfloat16 h; } cv;
    cv.u = u;
    return __bfloat162float(cv.h);
}

// ---------------- zero the global accumulator (64 x 33 floats) ----------------
__global__ __launch_bounds__(256) void zero_acc_kernel(float* __restrict__ gacc) {
    int i = blockIdx.x * 256 + threadIdx.x;
    if (i < NS * (SD + 1)) gacc[i] = 0.0f;
}

// ---------------- pack W1 -> bf16 hi/lo, MFMA-fragment order ----------------
// frag (kb, n): lane l, elem j  ->  W1[kb*32 + (l>>4)*8 + j][n*16 + (l&15)]
// stored lane-linear: idx = ((kb*4 + n)*64 + l)*8 + j   (each lane's 8 elems = 16B)
__global__ __launch_bounds__(256) void pack_w1_kernel(const float* __restrict__ W1,
                                                      unsigned short* __restrict__ W1h,
                                                      unsigned short* __restrict__ W1l) {
    int idx = blockIdx.x * 256 + threadIdx.x;   // 0..65535
    int j  = idx & 7;
    int l  = (idx >> 3) & 63;
    int n  = (idx >> 9) & 3;
    int kb = idx >> 11;
    int k  = kb * 32 + (l >> 4) * 8 + j;
    int c  = n * 16 + (l & 15);
    float w = W1[k * HID + c];
    unsigned short hu = f2bf(w);
    W1h[idx] = hu;
    W1l[idx] = f2bf(w - bf2f(hu));
}

struct StepBuf {
    float4 a[2][2];        // [row-frag m][k-half]
    bf16x8 bh[4], bl[4];   // [col-frag n]
};

__device__ __forceinline__ void load_step(StepBuf& s,
                                          const float* __restrict__ A0p, const float* __restrict__ A1p,
                                          const unsigned short* __restrict__ W1h,
                                          const unsigned short* __restrict__ W1l,
                                          int kb, int l) {
    const int K0 = kb * 32;
    s.a[0][0] = *(const float4*)(A0p + K0);
    s.a[0][1] = *(const float4*)(A0p + K0 + 4);
    s.a[1][0] = *(const float4*)(A1p + K0);
    s.a[1][1] = *(const float4*)(A1p + K0 + 4);
    const size_t fb = (size_t)kb * 2048 + (size_t)l * 8;  // (kb*4+n)*512 + l*8
    #pragma unroll
    for (int n = 0; n < 4; ++n) {
        s.bh[n] = *(const bf16x8*)(W1h + fb + (size_t)n * 512);
        s.bl[n] = *(const bf16x8*)(W1l + fb + (size_t)n * 512);
    }
}

__device__ __forceinline__ void cvt_split(const float4 a, const float4 b, bf16x8& hi, bf16x8& lo) {
    float f[8] = {a.x, a.y, a.z, a.w, b.x, b.y, b.z, b.w};
    #pragma unroll
    for (int j = 0; j < 8; ++j) {
        unsigned short hu = f2bf(f[j]);
        hi[j] = (short)hu;
        lo[j] = (short)f2bf(f[j] - bf2f(hu));
    }
}

__device__ __forceinline__ void comp_step(const StepBuf& s, f32x4 (&acc)[2][4]) {
    bf16x8 ah[2], al[2];
    #pragma unroll
    for (int m = 0; m < 2; ++m) cvt_split(s.a[m][0], s.a[m][1], ah[m], al[m]);
    #pragma unroll
    for (int m = 0; m < 2; ++m)
        #pragma unroll
        for (int n = 0; n < 4; ++n) {
            acc[m][n] = __builtin_amdgcn_mfma_f32_16x16x32_bf16(ah[m], s.bh[n], acc[m][n], 0, 0, 0);
            acc[m][n] = __builtin_amdgcn_mfma_f32_16x16x32_bf16(al[m], s.bh[n], acc[m][n], 0, 0, 0);
            acc[m][n] = __builtin_amdgcn_mfma_f32_16x16x32_bf16(ah[m], s.bl[n], acc[m][n], 0, 0, 0);
        }
}

// ---------------- main fused kernel: MFMA GEMM1 + encode + argmax + scatter ----------------
// LDS diet: union(hs 33.3 KB | {Sn, accl} 16.6 KB) = 33.3 KB total -> 4 blocks/CU.
// grid = 1024 = 4 x 256 CU: all blocks co-resident, zero tail.
__global__ __launch_bounds__(256, 4) void neo_main_kernel(
    const float* __restrict__ traces,
    const unsigned short* __restrict__ W1h, const unsigned short* __restrict__ W1l,
    const float* __restrict__ b1,     const float* __restrict__ W2,
    const float* __restrict__ b2,     const float* __restrict__ schemas,
    float* __restrict__ gacc)
{
    __shared__ union SM {
        float hs[TM][HID + 1];                                      // 33280 B (GEMM epilogue phase)
        struct { float Sn[NS][SD]; float accl[NS][SD + 1]; } p2;    // 16640 B (argmax phase)
    } sm;

    const int t  = threadIdx.x;
    const int l  = t & 63;
    const int wq = t >> 6;       // wave id 0..3 -> rows wq*32..wq*32+31
    const int lr = l & 15;       // row-in-frag (A) / col-in-frag (B,C)
    const int lg = l >> 4;       // k-group / C row-group

    // ---- GEMM1 via split-bf16 MFMA: (128 x 1024) @ (1024 x 64) ----
    const float* A0p = traces + (size_t)(blockIdx.x * TM + wq * 32 + lr) * DIM + lg * 8;
    const float* A1p = A0p + (size_t)16 * DIM;

    f32x4 acc[2][4];
    #pragma unroll
    for (int m = 0; m < 2; ++m)
        #pragma unroll
        for (int n = 0; n < 4; ++n) acc[m][n] = (f32x4){0.f, 0.f, 0.f, 0.f};

    StepBuf s0, s1;
    load_step(s0, A0p, A1p, W1h, W1l, 0, l);
    for (int kb = 0; kb < 32; kb += 2) {
        load_step(s1, A0p, A1p, W1h, W1l, kb + 1, l);
        comp_step(s0, acc);
        if (kb + 2 < 32) load_step(s0, A0p, A1p, W1h, W1l, kb + 2, l);
        comp_step(s1, acc);
    }

    // ---- h = relu(acc + b1) into LDS (MFMA C-layout: row=(l>>4)*4+r, col=n*16+(l&15)) ----
    {
        float b1v[4];
        #pragma unroll
        for (int n = 0; n < 4; ++n) b1v[n] = b1[n * 16 + lr];
        #pragma unroll
        for (int m = 0; m < 2; ++m)
            #pragma unroll
            for (int n = 0; n < 4; ++n)
                #pragma unroll
                for (int r = 0; r < 4; ++r) {
                    int row = wq * 32 + m * 16 + lg * 4 + r;
                    sm.hs[row][n * 16 + lr] = fmaxf(acc[m][n][r] + b1v[n], 0.0f);
                }
    }
    __syncthreads();

    // ---- encoded = h @ W2 + b2 : one thread per row, result stays in registers ----
    // W2 (8 KB) read lockstep-broadcast from global -> L1-resident.
    float enc[SD];
    if (t < TM) {
        #pragma unroll
        for (int c = 0; c < SD; ++c) enc[c] = b2[c];
        #pragma unroll 4
        for (int k = 0; k < HID; ++k) {
            float hk = sm.hs[t][k];
            #pragma unroll
            for (int c4 = 0; c4 < 8; ++c4) {
                float4 w = *(const float4*)(W2 + k * SD + c4 * 4);
                enc[c4 * 4 + 0] = fmaf(hk, w.x, enc[c4 * 4 + 0]);
                enc[c4 * 4 + 1] = fmaf(hk, w.y, enc[c4 * 4 + 1]);
                enc[c4 * 4 + 2] = fmaf(hk, w.z, enc[c4 * 4 + 2]);
                enc[c4 * 4 + 3] = fmaf(hk, w.w, enc[c4 * 4 + 3]);
            }
        }
    }
    __syncthreads();   // hs dead; union flips to {Sn, accl}

    // ---- normalized schemas + zero block-local accumulator ----
    if (t < NS) {
        float v[SD];
        float ss = 0.0f;
        #pragma unroll
        for (int c = 0; c < SD; ++c) { v[c] = schemas[t * SD + c]; ss += v[c] * v[c]; }
        float sc = 1.0f / fmaxf(sqrtf(ss), EPSc);
        #pragma unroll
        for (int c = 0; c < SD; ++c) sm.p2.Sn[t][c] = v[c] * sc;
    }
    for (int i = t; i < NS * (SD + 1); i += 256)
        (&sm.p2.accl[0][0])[i] = 0.0f;
    __syncthreads();

    // ---- argmax + block-local scatter (enc already in registers) ----
    if (t < TM) {
        // per-row positive normalization can't change argmax -> skip it
        float best = -INFINITY;
        int bi = 0;
        for (int s = 0; s < NS; ++s) {
            float d = 0.0f;
            #pragma unroll
            for (int c4 = 0; c4 < 8; ++c4) {
                float4 sv = *(const float4*)&sm.p2.Sn[s][c4 * 4];
                d = fmaf(enc[c4 * 4 + 0], sv.x, d);
                d = fmaf(enc[c4 * 4 + 1], sv.y, d);
                d = fmaf(enc[c4 * 4 + 2], sv.z, d);
                d = fmaf(enc[c4 * 4 + 3], sv.w, d);
            }
            if (d > best) { best = d; bi = s; }   // strict > keeps first max (jnp semantics)
        }
        atomicAdd(&sm.p2.accl[bi][SD], 1.0f);
        #pragma unroll
        for (int c = 0; c < SD; ++c) atomicAdd(&sm.p2.accl[bi][c], enc[c]);
    }
    __syncthreads();

    // ---- flush block partials to global accumulator ----
    for (int i = t; i < NS * (SD + 1); i += 256)
        atomicAdd(&gacc[i], (&sm.p2.accl[0][0])[i]);
}

// ---------------- finalize: schema update + stats ----------------
__global__ __launch_bounds__(64) void neo_finalize_kernel(
    const float* __restrict__ gacc, const float* __restrict__ schemas,
    const float* __restrict__ usage, float* __restrict__ out)
{
    const int s = threadIdx.x;   // 64 threads, 1 wave
    float count = gacc[s * (SD + 1) + SD];
    bool  ne    = count > 0.0f;
    float invc  = 1.0f / fmaxf(count, 1.0f);

    float nsq = 0.0f;
    #pragma unroll
    for (int c = 0; c < SD; ++c) {
        float sum    = gacc[s * (SD + 1) + c];
        float sch    = schemas[s * SD + c];
        float target = sum * invc;
        float delta  = ne ? (LRc * (target - sch)) : 0.0f;
        out[s * SD + c] = sch + delta;
        nsq = fmaf(delta, delta, nsq);
    }
    out[NS * SD + s] = usage[s] + count;

    float nrm = sqrtf(nsq);
    int nu = ne ? 1 : 0;
    #pragma unroll
    for (int off = 32; off > 0; off >>= 1) {
        nrm += __shfl_down(nrm, off);
        nu  += __shfl_down(nu, off);
    }
    if (s == 0) {
        out[NS * SD + NS]     = (float)nu;
        out[NS * SD + NS + 1] = nrm / (float)(nu > 0 ? nu : 1);
    }
}

extern "C" void kernel_launch(void* const* d_in, const int* in_sizes, int n_in,
                              void* d_out, int out_size, void* d_ws, size_t ws_size,
                              hipStream_t stream) {
    const float* traces  = (const float*)d_in[0];
    const float* W1      = (const float*)d_in[1];
    const float* b1      = (const float*)d_in[2];
    const float* W2      = (const float*)d_in[3];
    const float* b2      = (const float*)d_in[4];
    const float* schemas = (const float*)d_in[5];
    const float* usage   = (const float*)d_in[6];
    float* out  = (float*)d_out;

    float* gacc = (float*)d_ws;                                        // 8448 B
    unsigned short* W1h = (unsigned short*)((char*)d_ws + 16384);      // 128 KB
    unsigned short* W1l = (unsigned short*)((char*)d_ws + 16384 + 131072);

    const int N = in_sizes[0] / DIM;
    const int nblk = N / TM;

    hipLaunchKernelGGL(pack_w1_kernel, dim3(DIM * HID / 256), dim3(256), 0, stream, W1, W1h, W1l);
    hipLaunchKernelGGL(zero_acc_kernel, dim3((NS * (SD + 1) + 255) / 256), dim3(256), 0, stream, gacc);
    hipLaunchKernelGGL(neo_main_kernel, dim3(nblk), dim3(256), 0, stream,
                       traces, W1h, W1l, b1, W2, b2, schemas, gacc);
    hipLaunchKernelGGL(neo_finalize_kernel, dim3(1), dim3(64), 0, stream,
                       gacc, schemas, usage, out);
}

// Round 5
// 193.115 us; speedup vs baseline: 1.2966x; 1.2966x over previous
//
#include <hip/hip_runtime.h>
#include <hip/hip_bf16.h>
#include <math.h>

#define DIM 1024
#define HID 64
#define SD  32
#define NS  64
#define TM  128
#define LRc 0.01f
#define EPSc 1e-8f

typedef __attribute__((ext_vector_type(8))) short bf16x8;
typedef __attribute__((ext_vector_type(4))) float f32x4;

__device__ __forceinline__ unsigned short f2bf(float f) {
    union { __hip_bfloat16 h; unsigned short u; } cv;
    cv.h = __float2bfloat16(f);
    return cv.u;
}
__device__ __forceinline__ float bf2f(unsigned short u) {
    union { unsigned short u; __hip_bfloat16 h; } cv;
    cv.u = u;
    return __bfloat162float(cv.h);
}

// ---------------- zero the global accumulator (64 x 33 floats) ----------------
__global__ __launch_bounds__(256) void zero_acc_kernel(float* __restrict__ gacc) {
    int i = blockIdx.x * 256 + threadIdx.x;
    if (i < NS * (SD + 1)) gacc[i] = 0.0f;
}

// ---------------- pack W1 -> bf16 hi/lo, MFMA-fragment order ----------------
// frag (kb, n): lane l, elem j  ->  W1[kb*32 + (l>>4)*8 + j][n*16 + (l&15)]
// stored lane-linear: idx = ((kb*4 + n)*64 + l)*8 + j   (each lane's 8 elems = 16B)
__global__ __launch_bounds__(256) void pack_w1_kernel(const float* __restrict__ W1,
                                                      unsigned short* __restrict__ W1h,
                                                      unsigned short* __restrict__ W1l) {
    int idx = blockIdx.x * 256 + threadIdx.x;   // 0..65535
    int j  = idx & 7;
    int l  = (idx >> 3) & 63;
    int n  = (idx >> 9) & 3;
    int kb = idx >> 11;
    int k  = kb * 32 + (l >> 4) * 8 + j;
    int c  = n * 16 + (l & 15);
    float w = W1[k * HID + c];
    unsigned short hu = f2bf(w);
    W1h[idx] = hu;
    W1l[idx] = f2bf(w - bf2f(hu));
}

// ---- A loads: raw float4, 2-deep double buffer (HBM ~900cyc needs lookahead) ----
__device__ __forceinline__ void load_A(float4 (&a)[2][2],
                                       const float* __restrict__ A0p,
                                       const float* __restrict__ A1p, int kb) {
    const int K0 = kb * 32;
    a[0][0] = *(const float4*)(A0p + K0);
    a[0][1] = *(const float4*)(A0p + K0 + 4);
    a[1][0] = *(const float4*)(A1p + K0);
    a[1][1] = *(const float4*)(A1p + K0 + 4);
}

// ---- B loads: single-buffered JIT (W1h/l are 256KB, L2-resident ~200cyc; the
//      ~128cyc A cvt covers most of it; saves 32 VGPR vs double-buffering) ----
__device__ __forceinline__ void load_B(bf16x8 (&bh)[4], bf16x8 (&bl)[4],
                                       const unsigned short* __restrict__ W1h,
                                       const unsigned short* __restrict__ W1l,
                                       int kb, int l) {
    const size_t fb = (size_t)kb * 2048 + (size_t)l * 8;  // (kb*4+n)*512 + l*8
    #pragma unroll
    for (int n = 0; n < 4; ++n) {
        bh[n] = *(const bf16x8*)(W1h + fb + (size_t)n * 512);
        bl[n] = *(const bf16x8*)(W1l + fb + (size_t)n * 512);
    }
}

__device__ __forceinline__ void cvt_split(const float4 a, const float4 b, bf16x8& hi, bf16x8& lo) {
    float f[8] = {a.x, a.y, a.z, a.w, b.x, b.y, b.z, b.w};
    #pragma unroll
    for (int j = 0; j < 8; ++j) {
        unsigned short hu = f2bf(f[j]);
        hi[j] = (short)hu;
        lo[j] = (short)f2bf(f[j] - bf2f(hu));
    }
}

__device__ __forceinline__ void comp_step(const float4 (&a)[2][2],
                                          const bf16x8 (&bh)[4], const bf16x8 (&bl)[4],
                                          f32x4 (&acc)[2][4]) {
    bf16x8 ah[2], al[2];
    cvt_split(a[0][0], a[0][1], ah[0], al[0]);
    cvt_split(a[1][0], a[1][1], ah[1], al[1]);
    #pragma unroll
    for (int m = 0; m < 2; ++m)
        #pragma unroll
        for (int n = 0; n < 4; ++n) {
            acc[m][n] = __builtin_amdgcn_mfma_f32_16x16x32_bf16(ah[m], bh[n], acc[m][n], 0, 0, 0);
            acc[m][n] = __builtin_amdgcn_mfma_f32_16x16x32_bf16(al[m], bh[n], acc[m][n], 0, 0, 0);
            acc[m][n] = __builtin_amdgcn_mfma_f32_16x16x32_bf16(ah[m], bl[n], acc[m][n], 0, 0, 0);
        }
}

// ---------------- main fused kernel: MFMA GEMM1 + encode + argmax + scatter ----------------
// LDS 33.3 KB (union) -> LDS allows 4 blocks/CU; launch_bounds(256,3) keeps the
// VGPR allocator at <=~168 (round-4 lesson: the (256,4)=128 cap caused K-loop
// scratch spills and a 172->250us regression). If actual VGPR <=128 HW still
// schedules 4 blocks/CU.
__global__ __launch_bounds__(256, 3) void neo_main_kernel(
    const float* __restrict__ traces,
    const unsigned short* __restrict__ W1h, const unsigned short* __restrict__ W1l,
    const float* __restrict__ b1,     const float* __restrict__ W2,
    const float* __restrict__ b2,     const float* __restrict__ schemas,
    float* __restrict__ gacc)
{
    __shared__ union SM {
        float hs[TM][HID + 1];                                      // 33280 B (GEMM epilogue phase)
        struct { float Sn[NS][SD]; float accl[NS][SD + 1]; } p2;    // 16640 B (argmax phase)
    } sm;

    const int t  = threadIdx.x;
    const int l  = t & 63;
    const int wq = t >> 6;       // wave id 0..3 -> rows wq*32..wq*32+31
    const int lr = l & 15;       // row-in-frag (A) / col-in-frag (B,C)
    const int lg = l >> 4;       // k-group / C row-group

    // ---- GEMM1 via split-bf16 MFMA: (128 x 1024) @ (1024 x 64) ----
    const float* A0p = traces + (size_t)(blockIdx.x * TM + wq * 32 + lr) * DIM + lg * 8;
    const float* A1p = A0p + (size_t)16 * DIM;

    f32x4 acc[2][4];
    #pragma unroll
    for (int m = 0; m < 2; ++m)
        #pragma unroll
        for (int n = 0; n < 4; ++n) acc[m][n] = (f32x4){0.f, 0.f, 0.f, 0.f};

    float4 aA[2][2], aB[2][2];
    bf16x8 bh[4], bl[4];
    load_A(aA, A0p, A1p, 0);
    for (int kb = 0; kb < 32; kb += 2) {
        load_A(aB, A0p, A1p, kb + 1);
        load_B(bh, bl, W1h, W1l, kb, l);
        comp_step(aA, bh, bl, acc);
        if (kb + 2 < 32) load_A(aA, A0p, A1p, kb + 2);
        load_B(bh, bl, W1h, W1l, kb + 1, l);
        comp_step(aB, bh, bl, acc);
    }

    // ---- h = relu(acc + b1) into LDS (MFMA C-layout: row=(l>>4)*4+r, col=n*16+(l&15)) ----
    {
        float b1v[4];
        #pragma unroll
        for (int n = 0; n < 4; ++n) b1v[n] = b1[n * 16 + lr];
        #pragma unroll
        for (int m = 0; m < 2; ++m)
            #pragma unroll
            for (int n = 0; n < 4; ++n)
                #pragma unroll
                for (int r = 0; r < 4; ++r) {
                    int row = wq * 32 + m * 16 + lg * 4 + r;
                    sm.hs[row][n * 16 + lr] = fmaxf(acc[m][n][r] + b1v[n], 0.0f);
                }
    }
    __syncthreads();

    // ---- encoded = h @ W2 + b2 : one thread per row, result stays in registers ----
    // W2 (8 KB) read lockstep-broadcast from global -> L1-resident.
    float enc[SD];
    if (t < TM) {
        #pragma unroll
        for (int c = 0; c < SD; ++c) enc[c] = b2[c];
        #pragma unroll 4
        for (int k = 0; k < HID; ++k) {
            float hk = sm.hs[t][k];
            #pragma unroll
            for (int c4 = 0; c4 < 8; ++c4) {
                float4 w = *(const float4*)(W2 + k * SD + c4 * 4);
                enc[c4 * 4 + 0] = fmaf(hk, w.x, enc[c4 * 4 + 0]);
                enc[c4 * 4 + 1] = fmaf(hk, w.y, enc[c4 * 4 + 1]);
                enc[c4 * 4 + 2] = fmaf(hk, w.z, enc[c4 * 4 + 2]);
                enc[c4 * 4 + 3] = fmaf(hk, w.w, enc[c4 * 4 + 3]);
            }
        }
    }
    __syncthreads();   // hs dead; union flips to {Sn, accl}

    // ---- normalized schemas + zero block-local accumulator ----
    if (t < NS) {
        float v[SD];
        float ss = 0.0f;
        #pragma unroll
        for (int c = 0; c < SD; ++c) { v[c] = schemas[t * SD + c]; ss += v[c] * v[c]; }
        float sc = 1.0f / fmaxf(sqrtf(ss), EPSc);
        #pragma unroll
        for (int c = 0; c < SD; ++c) sm.p2.Sn[t][c] = v[c] * sc;
    }
    for (int i = t; i < NS * (SD + 1); i += 256)
        (&sm.p2.accl[0][0])[i] = 0.0f;
    __syncthreads();

    // ---- argmax + block-local scatter (enc already in registers) ----
    if (t < TM) {
        // per-row positive normalization can't change argmax -> skip it
        float best = -INFINITY;
        int bi = 0;
        for (int s = 0; s < NS; ++s) {
            float d = 0.0f;
            #pragma unroll
            for (int c4 = 0; c4 < 8; ++c4) {
                float4 sv = *(const float4*)&sm.p2.Sn[s][c4 * 4];
                d = fmaf(enc[c4 * 4 + 0], sv.x, d);
                d = fmaf(enc[c4 * 4 + 1], sv.y, d);
                d = fmaf(enc[c4 * 4 + 2], sv.z, d);
                d = fmaf(enc[c4 * 4 + 3], sv.w, d);
            }
            if (d > best) { best = d; bi = s; }   // strict > keeps first max (jnp semantics)
        }
        atomicAdd(&sm.p2.accl[bi][SD], 1.0f);
        #pragma unroll
        for (int c = 0; c < SD; ++c) atomicAdd(&sm.p2.accl[bi][c], enc[c]);
    }
    __syncthreads();

    // ---- flush block partials to global accumulator ----
    for (int i = t; i < NS * (SD + 1); i += 256)
        atomicAdd(&gacc[i], (&sm.p2.accl[0][0])[i]);
}

// ---------------- finalize: schema update + stats ----------------
__global__ __launch_bounds__(64) void neo_finalize_kernel(
    const float* __restrict__ gacc, const float* __restrict__ schemas,
    const float* __restrict__ usage, float* __restrict__ out)
{
    const int s = threadIdx.x;   // 64 threads, 1 wave
    float count = gacc[s * (SD + 1) + SD];
    bool  ne    = count > 0.0f;
    float invc  = 1.0f / fmaxf(count, 1.0f);

    float nsq = 0.0f;
    #pragma unroll
    for (int c = 0; c < SD; ++c) {
        float sum    = gacc[s * (SD + 1) + c];
        float sch    = schemas[s * SD + c];
        float target = sum * invc;
        float delta  = ne ? (LRc * (target - sch)) : 0.0f;
        out[s * SD + c] = sch + delta;
        nsq = fmaf(delta, delta, nsq);
    }
    out[NS * SD + s] = usage[s] + count;

    float nrm = sqrtf(nsq);
    int nu = ne ? 1 : 0;
    #pragma unroll
    for (int off = 32; off > 0; off >>= 1) {
        nrm += __shfl_down(nrm, off);
        nu  += __shfl_down(nu, off);
    }
    if (s == 0) {
        out[NS * SD + NS]     = (float)nu;
        out[NS * SD + NS + 1] = nrm / (float)(nu > 0 ? nu : 1);
    }
}

extern "C" void kernel_launch(void* const* d_in, const int* in_sizes, int n_in,
                              void* d_out, int out_size, void* d_ws, size_t ws_size,
                              hipStream_t stream) {
    const float* traces  = (const float*)d_in[0];
    const float* W1      = (const float*)d_in[1];
    const float* b1      = (const float*)d_in[2];
    const float* W2      = (const float*)d_in[3];
    const float* b2      = (const float*)d_in[4];
    const float* schemas = (const float*)d_in[5];
    const float* usage   = (const float*)d_in[6];
    float* out  = (float*)d_out;

    float* gacc = (float*)d_ws;                                        // 8448 B
    unsigned short* W1h = (unsigned short*)((char*)d_ws + 16384);      // 128 KB
    unsigned short* W1l = (unsigned short*)((char*)d_ws + 16384 + 131072);

    const int N = in_sizes[0] / DIM;
    const int nblk = N / TM;

    hipLaunchKernelGGL(pack_w1_kernel, dim3(DIM * HID / 256), dim3(256), 0, stream, W1, W1h, W1l);
    hipLaunchKernelGGL(zero_acc_kernel, dim3((NS * (SD + 1) + 255) / 256), dim3(256), 0, stream, gacc);
    hipLaunchKernelGGL(neo_main_kernel, dim3(nblk), dim3(256), 0, stream,
                       traces, W1h, W1l, b1, W2, b2, schemas, gacc);
    hipLaunchKernelGGL(neo_finalize_kernel, dim3(1), dim3(64), 0, stream,
                       gacc, schemas, usage, out);
}